// Round 1
// baseline (43358.408 us; speedup 1.0000x reference)
//
#include <hip/hip_runtime.h>

// ---------------- problem constants ----------------
#define TT 2048
#define BB 64
#define HH 256

#define NW0 32          // layer-0 workgroups (8 h-dims each, all 64 batches)
#define NW1 64          // layer-1 workgroups (8 h-dims x 32-batch half)
#define NWG 97          // 32 + 64 + 1 FC
#define NTHR 256

// ---------------- workspace layout (bytes) ----------------
#define WS_FLAGS 0                   // u32[128]
#define WS_GO    512                 // u32
#define WS_S0    1024                // [2 buf][2 comp][32 kblk][64 b][8] bf16 = 131072 B
#define WS_S1    (1024 + 131072)
#define WS_TOTAL (1024 + 2*131072)

// ---------------- LDS layouts (byte offsets into dynamic smem) ----------------
// Layer-0 role:
#define L0_AHI 0          // [32 kblk][32 row][8] bf16 (16 KB)
#define L0_ALO 16384
#define L0_BHI 32768      // [32 kblk][64 b][8] bf16 (32 KB)
#define L0_BLO 65536
#define L0_P   98304      // [32][68] f32 (8704 B)
#define L0_C   107008     // [512] f32
#define L0_WIB 109056     // [32] f32
#define L0_BIAS 109184    // [32] f32
#define L0_X   109312     // [64] f32
// Layer-1 role:
#define L1_AIH_HI 0       // each [32 kblk][32 row][8] bf16 (16 KB)
#define L1_AIH_LO 16384
#define L1_AHH_HI 32768
#define L1_AHH_LO 49152
#define L1_B1HI   65536   // each [32 kblk][32 b][8] bf16 (16 KB)
#define L1_B1LO   81920
#define L1_B2HI   98304
#define L1_B2LO   114688
#define L1_P      131072  // [64][36] f32 (9216 B)
#define L1_C      140288  // [256] f32
#define L1_BIAS   141312  // [32] f32
#define SMEM_BYTES 141440

typedef __bf16 bf16;
typedef __bf16 bf16x8 __attribute__((ext_vector_type(8)));
typedef float f32x4 __attribute__((ext_vector_type(4)));
typedef unsigned int u32;

__device__ __forceinline__ f32x4 MFMA(bf16x8 a, bf16x8 b, f32x4 c) {
  return __builtin_amdgcn_mfma_f32_16x16x32_bf16(a, b, c, 0, 0, 0);
}
__device__ __forceinline__ float sigf(float v) { return 1.0f / (1.0f + __expf(-v)); }

// device-scope barrier: per-WG monotonic flag, WG0 wave0 polls, broadcasts "go".
__device__ __forceinline__ void gbar(u32* flags, u32* go, u32 v) {
  __syncthreads();
  __threadfence();  // release: flush this XCD's L2 (data stores already drained by syncthreads)
  if (threadIdx.x == 0)
    __hip_atomic_store(&flags[blockIdx.x], v, __ATOMIC_RELEASE, __HIP_MEMORY_SCOPE_AGENT);
  if (blockIdx.x == 0 && threadIdx.x < 64) {
    const int l = threadIdx.x;
    for (;;) {
      u32 a = __hip_atomic_load(&flags[l], __ATOMIC_RELAXED, __HIP_MEMORY_SCOPE_AGENT);
      u32 b = (l + 64 < NWG) ? __hip_atomic_load(&flags[l + 64], __ATOMIC_RELAXED, __HIP_MEMORY_SCOPE_AGENT) : v;
      if (__all((int)(a >= v && b >= v))) break;
      __builtin_amdgcn_s_sleep(1);
    }
    if (l == 0)
      __hip_atomic_store(go, v, __ATOMIC_RELEASE, __HIP_MEMORY_SCOPE_AGENT);
  }
  if (threadIdx.x == 0) {
    while (__hip_atomic_load(go, __ATOMIC_RELAXED, __HIP_MEMORY_SCOPE_AGENT) < v)
      __builtin_amdgcn_s_sleep(1);
  }
  __threadfence();  // acquire: invalidate stale lines before reading remote h
  __syncthreads();
}

// S-buffer pointer: [buf][comp] blocks of 32*64*8 = 16384 bf16
#define SPTR(base, buf, comp) ((base) + (((buf)*2 + (comp)) << 14))

extern "C" __global__ __launch_bounds__(NTHR)
void lstm_persist(const float* __restrict__ x,
                  const float* __restrict__ Wih0, const float* __restrict__ Whh0,
                  const float* __restrict__ bih0, const float* __restrict__ bhh0,
                  const float* __restrict__ Wih1, const float* __restrict__ Whh1,
                  const float* __restrict__ bih1, const float* __restrict__ bhh1,
                  const float* __restrict__ fcw, const float* __restrict__ fcb,
                  float* __restrict__ out, char* __restrict__ ws)
{
  extern __shared__ char smem[];
  const int tid = threadIdx.x;
  const int wg = blockIdx.x;
  u32* flags = (u32*)(ws + WS_FLAGS);
  u32* go    = (u32*)(ws + WS_GO);
  bf16* S0 = (bf16*)(ws + WS_S0);
  bf16* S1 = (bf16*)(ws + WS_S1);

  if (wg < NW0) {
    // ================= LAYER-0 WG: dims [wg*8, wg*8+8), batches 0..63 =================
    bf16x8* Ahi = (bf16x8*)(smem + L0_AHI);
    bf16x8* Alo = (bf16x8*)(smem + L0_ALO);
    float* wib  = (float*)(smem + L0_WIB);
    float* bias = (float*)(smem + L0_BIAS);
    float* cbuf = (float*)(smem + L0_C);
    float* xb   = (float*)(smem + L0_X);

    // one-time: load Whh0 slice as split-bf16 in k-panel fragment layout
    for (int i = tid; i < 32 * 32; i += NTHR) {  // i = row*32 + kblk
      int row = i >> 5, kb = i & 31;
      int gate = row >> 3, d = row & 7;
      int grow = gate * 256 + wg * 8 + d;
      const float* src = Whh0 + grow * 256 + kb * 8;
      bf16x8 hi, lo;
#pragma unroll
      for (int e = 0; e < 8; e++) {
        float v = src[e];
        bf16 h = (bf16)v;
        hi[e] = h;
        lo[e] = (bf16)(v - (float)h);
      }
      Ahi[kb * 32 + row] = hi;
      Alo[kb * 32 + row] = lo;
    }
    if (tid < 32) {
      int gate = tid >> 3, d = tid & 7;
      int grow = gate * 256 + wg * 8 + d;
      wib[tid]  = Wih0[grow];
      bias[tid] = bih0[grow] + bhh0[grow];
    }
    for (int i = tid; i < 512; i += NTHR) cbuf[i] = 0.0f;

    for (int s = 0; s <= TT + 1; s++) {
      if (s < TT) {
        // stage h0[s-1] fragments (hi+lo) into LDS; layout identical to global
        const uint4* gh = (const uint4*)SPTR(S0, (s - 1) & 1, 0);
        const uint4* gl = (const uint4*)SPTR(S0, (s - 1) & 1, 1);
        uint4* bh = (uint4*)(smem + L0_BHI);
        uint4* bl = (uint4*)(smem + L0_BLO);
        for (int i = tid; i < 2048; i += NTHR) { bh[i] = gh[i]; bl[i] = gl[i]; }
        if (tid < 64) xb[tid] = x[tid * TT + s];
        __syncthreads();

        const int w = tid >> 6, l = tid & 63, lr = l & 15, lk = l >> 4;
        const bf16x8* Ah = (const bf16x8*)(smem + L0_AHI);
        const bf16x8* Al = (const bf16x8*)(smem + L0_ALO);
        const bf16x8* Bh = (const bf16x8*)(smem + L0_BHI);
        const bf16x8* Bl = (const bf16x8*)(smem + L0_BLO);
        f32x4 acc0 = {0.f, 0.f, 0.f, 0.f}, acc1 = {0.f, 0.f, 0.f, 0.f};
#pragma unroll
        for (int ks = 0; ks < 8; ks++) {
          int kb = ks * 4 + lk;
          bf16x8 a0h = Ah[kb * 32 + lr],      a1h = Ah[kb * 32 + 16 + lr];
          bf16x8 a0l = Al[kb * 32 + lr],      a1l = Al[kb * 32 + 16 + lr];
          bf16x8 b_h = Bh[kb * 64 + w * 16 + lr];
          bf16x8 b_l = Bl[kb * 64 + w * 16 + lr];
          acc0 = MFMA(a0h, b_h, acc0);  acc1 = MFMA(a1h, b_h, acc1);
          acc0 = MFMA(a0h, b_l, acc0);  acc1 = MFMA(a1h, b_l, acc1);
          acc0 = MFMA(a0l, b_h, acc0);  acc1 = MFMA(a1l, b_h, acc1);
        }
        float* P = (float*)(smem + L0_P);
#pragma unroll
        for (int r = 0; r < 4; r++) {
          P[(lk * 4 + r) * 68 + w * 16 + lr]      = acc0[r];
          P[(16 + lk * 4 + r) * 68 + w * 16 + lr] = acc1[r];
        }
        __syncthreads();

        // gate update for (d, b); write h0[s] split-bf16 to S0[s&1]
        bf16* WHi = SPTR(S0, s & 1, 0);
        bf16* WLo = SPTR(S0, s & 1, 1);
        for (int i = tid; i < 512; i += NTHR) {
          int d = i >> 6, b = i & 63;
          float xv = xb[b];
          float pi = P[(d) * 68 + b]      + wib[d] * xv      + bias[d];
          float pf = P[(8 + d) * 68 + b]  + wib[8 + d] * xv  + bias[8 + d];
          float pg = P[(16 + d) * 68 + b] + wib[16 + d] * xv + bias[16 + d];
          float po = P[(24 + d) * 68 + b] + wib[24 + d] * xv + bias[24 + d];
          float c = sigf(pf) * cbuf[i] + sigf(pi) * tanhf(pg);
          cbuf[i] = c;
          float h = sigf(po) * tanhf(c);
          bf16 hh = (bf16)h;
          WHi[(wg * 64 + b) * 8 + d] = hh;
          WLo[(wg * 64 + b) * 8 + d] = (bf16)(h - (float)hh);
        }
      }
      if (s <= TT) gbar(flags, go, (u32)(s + 1));
    }
  } else if (wg < NW0 + NW1) {
    // ================= LAYER-1 WG: dims [dg*8,+8), batches [half*32,+32) =================
    const int wg1 = wg - NW0;
    const int dg = wg1 & 31;
    const int half = wg1 >> 5;
    bf16x8* AihH = (bf16x8*)(smem + L1_AIH_HI);
    bf16x8* AihL = (bf16x8*)(smem + L1_AIH_LO);
    bf16x8* AhhH = (bf16x8*)(smem + L1_AHH_HI);
    bf16x8* AhhL = (bf16x8*)(smem + L1_AHH_LO);
    float* bias1 = (float*)(smem + L1_BIAS);
    float* cbuf  = (float*)(smem + L1_C);

    for (int i = tid; i < 32 * 32; i += NTHR) {
      int row = i >> 5, kb = i & 31;
      int gate = row >> 3, d = row & 7;
      int grow = gate * 256 + dg * 8 + d;
      {
        const float* src = Wih1 + grow * 256 + kb * 8;
        bf16x8 hi, lo;
#pragma unroll
        for (int e = 0; e < 8; e++) { float v = src[e]; bf16 h = (bf16)v; hi[e] = h; lo[e] = (bf16)(v - (float)h); }
        AihH[kb * 32 + row] = hi; AihL[kb * 32 + row] = lo;
      }
      {
        const float* src = Whh1 + grow * 256 + kb * 8;
        bf16x8 hi, lo;
#pragma unroll
        for (int e = 0; e < 8; e++) { float v = src[e]; bf16 h = (bf16)v; hi[e] = h; lo[e] = (bf16)(v - (float)h); }
        AhhH[kb * 32 + row] = hi; AhhL[kb * 32 + row] = lo;
      }
    }
    if (tid < 32) {
      int gate = tid >> 3, d = tid & 7;
      int grow = gate * 256 + dg * 8 + d;
      bias1[tid] = bih1[grow] + bhh1[grow];
    }
    for (int i = tid; i < 256; i += NTHR) cbuf[i] = 0.0f;

    for (int s = 0; s <= TT + 1; s++) {
      if (s >= 1 && s <= TT) {
        const int rb = (s - 1) & 1;
        const uint4* g1h = (const uint4*)SPTR(S0, rb, 0);
        const uint4* g1l = (const uint4*)SPTR(S0, rb, 1);
        const uint4* g2h = (const uint4*)SPTR(S1, rb, 0);
        const uint4* g2l = (const uint4*)SPTR(S1, rb, 1);
        uint4* b1h = (uint4*)(smem + L1_B1HI);
        uint4* b1l = (uint4*)(smem + L1_B1LO);
        uint4* b2h = (uint4*)(smem + L1_B2HI);
        uint4* b2l = (uint4*)(smem + L1_B2LO);
        for (int i = tid; i < 1024; i += NTHR) {
          int kb = i >> 5, bl = i & 31;
          int gi = kb * 64 + half * 32 + bl;
          b1h[i] = g1h[gi]; b1l[i] = g1l[gi];
          b2h[i] = g2h[gi]; b2l[i] = g2l[gi];
        }
        __syncthreads();

        const int w = tid >> 6, l = tid & 63, lr = l & 15, lk = l >> 4;
        const int mat = w >> 1, ct = w & 1;
        const bf16x8* Ah = (const bf16x8*)(smem + (mat ? L1_AHH_HI : L1_AIH_HI));
        const bf16x8* Al = (const bf16x8*)(smem + (mat ? L1_AHH_LO : L1_AIH_LO));
        const bf16x8* Bh = (const bf16x8*)(smem + (mat ? L1_B2HI : L1_B1HI));
        const bf16x8* Bl = (const bf16x8*)(smem + (mat ? L1_B2LO : L1_B1LO));
        f32x4 acc0 = {0.f, 0.f, 0.f, 0.f}, acc1 = {0.f, 0.f, 0.f, 0.f};
#pragma unroll
        for (int ks = 0; ks < 8; ks++) {
          int kb = ks * 4 + lk;
          bf16x8 a0h = Ah[kb * 32 + lr],      a1h = Ah[kb * 32 + 16 + lr];
          bf16x8 a0l = Al[kb * 32 + lr],      a1l = Al[kb * 32 + 16 + lr];
          bf16x8 b_h = Bh[kb * 32 + ct * 16 + lr];
          bf16x8 b_l = Bl[kb * 32 + ct * 16 + lr];
          acc0 = MFMA(a0h, b_h, acc0);  acc1 = MFMA(a1h, b_h, acc1);
          acc0 = MFMA(a0h, b_l, acc0);  acc1 = MFMA(a1h, b_l, acc1);
          acc0 = MFMA(a0l, b_h, acc0);  acc1 = MFMA(a1l, b_h, acc1);
        }
        float* P = (float*)(smem + L1_P);
#pragma unroll
        for (int r = 0; r < 4; r++) {
          P[(mat * 32 + lk * 4 + r) * 36 + ct * 16 + lr]      = acc0[r];
          P[(mat * 32 + 16 + lk * 4 + r) * 36 + ct * 16 + lr] = acc1[r];
        }
        __syncthreads();

        bf16* WHi = SPTR(S1, s & 1, 0);
        bf16* WLo = SPTR(S1, s & 1, 1);
        {
          int d = tid >> 5, b = tid & 31;
          float pi = P[(d) * 36 + b]      + P[(32 + d) * 36 + b]      + bias1[d];
          float pf = P[(8 + d) * 36 + b]  + P[(32 + 8 + d) * 36 + b]  + bias1[8 + d];
          float pg = P[(16 + d) * 36 + b] + P[(32 + 16 + d) * 36 + b] + bias1[16 + d];
          float po = P[(24 + d) * 36 + b] + P[(32 + 24 + d) * 36 + b] + bias1[24 + d];
          float c = sigf(pf) * cbuf[tid] + sigf(pi) * tanhf(pg);
          cbuf[tid] = c;
          float h = sigf(po) * tanhf(c);
          bf16 hh = (bf16)h;
          WHi[(dg * 64 + half * 32 + b) * 8 + d] = hh;
          WLo[(dg * 64 + half * 32 + b) * 8 + d] = (bf16)(h - (float)hh);
        }
      }
      if (s <= TT) gbar(flags, go, (u32)(s + 1));
    }
  } else {
    // ================= FC WG: out[b,t] = fc_w . h2[t] + fc_b =================
    float* fw = (float*)smem;  // [256]
    for (int i = tid; i < 256; i += NTHR) fw[i] = fcw[i];
    __syncthreads();
    const float fb = fcb[0];
    for (int s = 0; s <= TT + 1; s++) {
      if (s >= 2) {
        int t = s - 2;
        const bf16x8* hi8 = (const bf16x8*)SPTR(S1, (s - 1) & 1, 0);
        const bf16x8* lo8 = (const bf16x8*)SPTR(S1, (s - 1) & 1, 1);
        if (tid < 64) {
          int b = tid;
          float acc = fb;
          for (int kb = 0; kb < 32; kb++) {
            bf16x8 vh = hi8[kb * 64 + b];
            bf16x8 vl = lo8[kb * 64 + b];
#pragma unroll
            for (int e = 0; e < 8; e++)
              acc += ((float)vh[e] + (float)vl[e]) * fw[kb * 8 + e];
          }
          out[b * TT + t] = acc;
        }
      }
      if (s <= TT) gbar(flags, go, (u32)(s + 1));
    }
  }
}

extern "C" void kernel_launch(void* const* d_in, const int* in_sizes, int n_in,
                              void* d_out, int out_size, void* d_ws, size_t ws_size,
                              hipStream_t stream) {
  (void)in_sizes; (void)n_in; (void)out_size; (void)ws_size;
  hipFuncSetAttribute((const void*)lstm_persist,
                      hipFuncAttributeMaxDynamicSharedMemorySize, SMEM_BYTES);
  // re-initialize barrier flags and zero h-state buffers every call (deterministic)
  hipMemsetAsync(d_ws, 0, WS_TOTAL, stream);
  lstm_persist<<<dim3(NWG), dim3(NTHR), SMEM_BYTES, stream>>>(
      (const float*)d_in[0],
      (const float*)d_in[1], (const float*)d_in[2],
      (const float*)d_in[3], (const float*)d_in[4],
      (const float*)d_in[5], (const float*)d_in[6],
      (const float*)d_in[7], (const float*)d_in[8],
      (const float*)d_in[9], (const float*)d_in[10],
      (float*)d_out, (char*)d_ws);
}

// Round 2
// 24564.929 us; speedup vs baseline: 1.7651x; 1.7651x over previous
//
#include <hip/hip_runtime.h>

// ---------------- problem constants ----------------
#define TT 2048
#define BB 64
#define HH 256

#define NW0 32          // layer-0 workgroups (8 h-dims each, all 64 batches)
#define NW1 64          // layer-1 workgroups (8 h-dims x 32-batch half)
#define NWG 97          // 32 + 64 + 1 FC
#define NTHR 256

// ---------------- workspace layout (bytes) ----------------
#define WS_FLAGS 0                   // u32[128]
#define WS_S0    1024                // [2 buf][2 comp][32 kblk][64 b][8] bf16 = 131072 B
#define WS_S1    (1024 + 131072)
#define WS_TOTAL (1024 + 2*131072)

// ---------------- LDS layouts (byte offsets into dynamic smem) ----------------
// Layer-0 role:
#define L0_AHI 0          // [32 kblk][32 row][8] bf16 (16 KB)
#define L0_ALO 16384
#define L0_BHI 32768      // [32 kblk][64 b][8] bf16 (32 KB)
#define L0_BLO 65536
#define L0_P   98304      // [32][68] f32 (8704 B)
#define L0_C   107008     // [512] f32
#define L0_WIB 109056     // [32] f32
#define L0_BIAS 109184    // [32] f32
#define L0_X   109312     // [64] f32
// Layer-1 role:
#define L1_AIH_HI 0       // each [32 kblk][32 row][8] bf16 (16 KB)
#define L1_AIH_LO 16384
#define L1_AHH_HI 32768
#define L1_AHH_LO 49152
#define L1_B1HI   65536   // each [32 kblk][32 b][8] bf16 (16 KB)
#define L1_B1LO   81920
#define L1_B2HI   98304
#define L1_B2LO   114688
#define L1_P      131072  // [64][36] f32 (9216 B)
#define L1_C      140288  // [256] f32
#define L1_BIAS   141312  // [32] f32
#define SMEM_BYTES 141440

typedef __bf16 bf16;
typedef __bf16 bf16x8 __attribute__((ext_vector_type(8)));
typedef __bf16 bf16x4 __attribute__((ext_vector_type(4)));
typedef float f32x4 __attribute__((ext_vector_type(4)));
typedef unsigned int u32;
typedef unsigned long long u64;
typedef unsigned short u16;

__device__ __forceinline__ f32x4 MFMA(bf16x8 a, bf16x8 b, f32x4 c) {
  return __builtin_amdgcn_mfma_f32_16x16x32_bf16(a, b, c, 0, 0, 0);
}
__device__ __forceinline__ float sigf(float v) { return 1.0f / (1.0f + __expf(-v)); }

// agent-scope (L2-bypassing) accessors — all cross-WG data goes through these,
// so NO buffer_inv / threadfence is ever required.
__device__ __forceinline__ u64 ld_agent64(const u64* p) {
  return __hip_atomic_load(p, __ATOMIC_RELAXED, __HIP_MEMORY_SCOPE_AGENT);
}
__device__ __forceinline__ void st_agent32(u32* p, u32 v) {
  __hip_atomic_store(p, v, __ATOMIC_RELAXED, __HIP_MEMORY_SCOPE_AGENT);
}

// single-round all-to-all device barrier.
// Release store on own flag (L2 is clean of cross-WG data -> wbl2 ~free);
// every WG's wave0 polls all 97 flags directly. No fences, no master, no 'go'.
__device__ __forceinline__ void gbar(u32* flags, u32 v) {
  __syncthreads();   // all waves' sc1 data stores drained (vmcnt 0) before flag
  if (threadIdx.x == 0)
    __hip_atomic_store(&flags[blockIdx.x], v, __ATOMIC_RELEASE, __HIP_MEMORY_SCOPE_AGENT);
  if (threadIdx.x < 64) {
    const int l = threadIdx.x;
    const bool two = (l + 64) < NWG;
    for (;;) {
      u32 a = __hip_atomic_load(&flags[l], __ATOMIC_RELAXED, __HIP_MEMORY_SCOPE_AGENT);
      u32 b = two ? __hip_atomic_load(&flags[l + 64], __ATOMIC_RELAXED, __HIP_MEMORY_SCOPE_AGENT) : v;
      if (__all((int)(a >= v && b >= v))) break;
    }
  }
  __syncthreads();
}

__device__ __forceinline__ u32 pack2(float a, float b) {
  u16 pa = __builtin_bit_cast(u16, (bf16)a);
  u16 pb = __builtin_bit_cast(u16, (bf16)b);
  return ((u32)pb << 16) | pa;
}

// S-buffer pointer: [buf][comp] blocks of 32*64*8 = 16384 bf16 (32 KB)
#define SPTR(base, buf, comp) ((base) + (((buf)*2 + (comp)) << 14))

extern "C" __global__ __launch_bounds__(NTHR)
void lstm_persist(const float* __restrict__ x,
                  const float* __restrict__ Wih0, const float* __restrict__ Whh0,
                  const float* __restrict__ bih0, const float* __restrict__ bhh0,
                  const float* __restrict__ Wih1, const float* __restrict__ Whh1,
                  const float* __restrict__ bih1, const float* __restrict__ bhh1,
                  const float* __restrict__ fcw, const float* __restrict__ fcb,
                  float* __restrict__ out, char* __restrict__ ws)
{
  extern __shared__ char smem[];
  const int tid = threadIdx.x;
  const int wg = blockIdx.x;
  u32* flags = (u32*)(ws + WS_FLAGS);
  bf16* S0 = (bf16*)(ws + WS_S0);
  bf16* S1 = (bf16*)(ws + WS_S1);

  if (wg < NW0) {
    // ================= LAYER-0 WG: dims [wg*8, wg*8+8), batches 0..63 =================
    bf16x8* Ahi = (bf16x8*)(smem + L0_AHI);
    bf16x8* Alo = (bf16x8*)(smem + L0_ALO);
    float* wib  = (float*)(smem + L0_WIB);
    float* bias = (float*)(smem + L0_BIAS);
    float* cbuf = (float*)(smem + L0_C);
    float* xb   = (float*)(smem + L0_X);

    // one-time: Whh0 slice -> split-bf16 k-panel fragments (normal cached loads)
    for (int i = tid; i < 32 * 32; i += NTHR) {  // i = row*32 + kblk
      int row = i >> 5, kb = i & 31;
      int gate = row >> 3, d = row & 7;
      int grow = gate * 256 + wg * 8 + d;
      const float* src = Whh0 + grow * 256 + kb * 8;
      bf16x8 hi, lo;
#pragma unroll
      for (int e = 0; e < 8; e++) {
        float v = src[e];
        bf16 h = (bf16)v;
        hi[e] = h;
        lo[e] = (bf16)(v - (float)h);
      }
      Ahi[kb * 32 + row] = hi;
      Alo[kb * 32 + row] = lo;
    }
    if (tid < 32) {
      int gate = tid >> 3, d = tid & 7;
      int grow = gate * 256 + wg * 8 + d;
      wib[tid]  = Wih0[grow];
      bias[tid] = bih0[grow] + bhh0[grow];
    }
    for (int i = tid; i < 512; i += NTHR) cbuf[i] = 0.0f;

    for (int s = 0; s <= TT + 1; s++) {
      if (s < TT) {
        // stage h0[s-1] (hi+lo) into LDS via agent-scope u64 loads
        const u64* gh = (const u64*)SPTR(S0, (s - 1) & 1, 0);
        const u64* gl = (const u64*)SPTR(S0, (s - 1) & 1, 1);
        u64* bh = (u64*)(smem + L0_BHI);
        u64* bl = (u64*)(smem + L0_BLO);
        for (int i = tid; i < 4096; i += NTHR) {
          bh[i] = ld_agent64(gh + i);
          bl[i] = ld_agent64(gl + i);
        }
        if (tid < 64) xb[tid] = x[tid * TT + s];   // cached; stays in L2 now
        __syncthreads();

        const int w = tid >> 6, l = tid & 63, lr = l & 15, lk = l >> 4;
        const bf16x8* Ah = (const bf16x8*)(smem + L0_AHI);
        const bf16x8* Al = (const bf16x8*)(smem + L0_ALO);
        const bf16x8* Bh = (const bf16x8*)(smem + L0_BHI);
        const bf16x8* Bl = (const bf16x8*)(smem + L0_BLO);
        f32x4 acc0 = {0.f, 0.f, 0.f, 0.f}, acc1 = {0.f, 0.f, 0.f, 0.f};
#pragma unroll
        for (int ks = 0; ks < 8; ks++) {
          int kb = ks * 4 + lk;
          bf16x8 a0h = Ah[kb * 32 + lr],      a1h = Ah[kb * 32 + 16 + lr];
          bf16x8 a0l = Al[kb * 32 + lr],      a1l = Al[kb * 32 + 16 + lr];
          bf16x8 b_h = Bh[kb * 64 + w * 16 + lr];
          bf16x8 b_l = Bl[kb * 64 + w * 16 + lr];
          acc0 = MFMA(a0h, b_h, acc0);  acc1 = MFMA(a1h, b_h, acc1);
          acc0 = MFMA(a0h, b_l, acc0);  acc1 = MFMA(a1h, b_l, acc1);
          acc0 = MFMA(a0l, b_h, acc0);  acc1 = MFMA(a1l, b_h, acc1);
        }
        float* P = (float*)(smem + L0_P);
#pragma unroll
        for (int r = 0; r < 4; r++) {
          P[(lk * 4 + r) * 68 + w * 16 + lr]      = acc0[r];
          P[(16 + lk * 4 + r) * 68 + w * 16 + lr] = acc1[r];
        }
        __syncthreads();

        // gate update; each thread does 2 adjacent dims for one batch, packs u32
        u32* WHi = (u32*)SPTR(S0, s & 1, 0);
        u32* WLo = (u32*)SPTR(S0, s & 1, 1);
        {
          int b = tid >> 2, p = tid & 3;
          float xv = xb[b];
          float hv[2], rv[2];
#pragma unroll
          for (int q = 0; q < 2; q++) {
            int d = p * 2 + q;
            float pi = P[(d) * 68 + b]      + wib[d] * xv      + bias[d];
            float pf = P[(8 + d) * 68 + b]  + wib[8 + d] * xv  + bias[8 + d];
            float pg = P[(16 + d) * 68 + b] + wib[16 + d] * xv + bias[16 + d];
            float po = P[(24 + d) * 68 + b] + wib[24 + d] * xv + bias[24 + d];
            float c = sigf(pf) * cbuf[d * 64 + b] + sigf(pi) * tanhf(pg);
            cbuf[d * 64 + b] = c;
            float h = sigf(po) * tanhf(c);
            hv[q] = h;
            rv[q] = h - (float)((bf16)h);
          }
          int widx = (wg * 64 + b) * 4 + p;
          st_agent32(WHi + widx, pack2(hv[0], hv[1]));
          st_agent32(WLo + widx, pack2(rv[0], rv[1]));
        }
      }
      if (s <= TT) gbar(flags, (u32)(s + 1));
    }
  } else if (wg < NW0 + NW1) {
    // ================= LAYER-1 WG: dims [dg*8,+8), batches [half*32,+32) =================
    const int wg1 = wg - NW0;
    const int dg = wg1 & 31;
    const int half = wg1 >> 5;
    bf16x8* AihH = (bf16x8*)(smem + L1_AIH_HI);
    bf16x8* AihL = (bf16x8*)(smem + L1_AIH_LO);
    bf16x8* AhhH = (bf16x8*)(smem + L1_AHH_HI);
    bf16x8* AhhL = (bf16x8*)(smem + L1_AHH_LO);
    float* bias1 = (float*)(smem + L1_BIAS);
    float* cbuf  = (float*)(smem + L1_C);

    for (int i = tid; i < 32 * 32; i += NTHR) {
      int row = i >> 5, kb = i & 31;
      int gate = row >> 3, d = row & 7;
      int grow = gate * 256 + dg * 8 + d;
      {
        const float* src = Wih1 + grow * 256 + kb * 8;
        bf16x8 hi, lo;
#pragma unroll
        for (int e = 0; e < 8; e++) { float v = src[e]; bf16 h = (bf16)v; hi[e] = h; lo[e] = (bf16)(v - (float)h); }
        AihH[kb * 32 + row] = hi; AihL[kb * 32 + row] = lo;
      }
      {
        const float* src = Whh1 + grow * 256 + kb * 8;
        bf16x8 hi, lo;
#pragma unroll
        for (int e = 0; e < 8; e++) { float v = src[e]; bf16 h = (bf16)v; hi[e] = h; lo[e] = (bf16)(v - (float)h); }
        AhhH[kb * 32 + row] = hi; AhhL[kb * 32 + row] = lo;
      }
    }
    if (tid < 32) {
      int gate = tid >> 3, d = tid & 7;
      int grow = gate * 256 + dg * 8 + d;
      bias1[tid] = bih1[grow] + bhh1[grow];
    }
    for (int i = tid; i < 256; i += NTHR) cbuf[i] = 0.0f;

    for (int s = 0; s <= TT + 1; s++) {
      if (s >= 1 && s <= TT) {
        const int rb = (s - 1) & 1;
        const u64* g1h = (const u64*)SPTR(S0, rb, 0);
        const u64* g1l = (const u64*)SPTR(S0, rb, 1);
        const u64* g2h = (const u64*)SPTR(S1, rb, 0);
        const u64* g2l = (const u64*)SPTR(S1, rb, 1);
        u64* b1h = (u64*)(smem + L1_B1HI);
        u64* b1l = (u64*)(smem + L1_B1LO);
        u64* b2h = (u64*)(smem + L1_B2HI);
        u64* b2l = (u64*)(smem + L1_B2LO);
        for (int i = tid; i < 2048; i += NTHR) {
          // LDS u64 idx i = kb*64 + (b*2+j), b<32 ; global idx = kb*128 + half*64 + (b*2+j)
          int gi = i + ((i >> 6) << 6) + half * 64;
          b1h[i] = ld_agent64(g1h + gi);
          b1l[i] = ld_agent64(g1l + gi);
          b2h[i] = ld_agent64(g2h + gi);
          b2l[i] = ld_agent64(g2l + gi);
        }
        __syncthreads();

        const int w = tid >> 6, l = tid & 63, lr = l & 15, lk = l >> 4;
        const int mat = w >> 1, ct = w & 1;
        const bf16x8* Ah = (const bf16x8*)(smem + (mat ? L1_AHH_HI : L1_AIH_HI));
        const bf16x8* Al = (const bf16x8*)(smem + (mat ? L1_AHH_LO : L1_AIH_LO));
        const bf16x8* Bh = (const bf16x8*)(smem + (mat ? L1_B2HI : L1_B1HI));
        const bf16x8* Bl = (const bf16x8*)(smem + (mat ? L1_B2LO : L1_B1LO));
        f32x4 acc0 = {0.f, 0.f, 0.f, 0.f}, acc1 = {0.f, 0.f, 0.f, 0.f};
#pragma unroll
        for (int ks = 0; ks < 8; ks++) {
          int kb = ks * 4 + lk;
          bf16x8 a0h = Ah[kb * 32 + lr],      a1h = Ah[kb * 32 + 16 + lr];
          bf16x8 a0l = Al[kb * 32 + lr],      a1l = Al[kb * 32 + 16 + lr];
          bf16x8 b_h = Bh[kb * 32 + ct * 16 + lr];
          bf16x8 b_l = Bl[kb * 32 + ct * 16 + lr];
          acc0 = MFMA(a0h, b_h, acc0);  acc1 = MFMA(a1h, b_h, acc1);
          acc0 = MFMA(a0h, b_l, acc0);  acc1 = MFMA(a1h, b_l, acc1);
          acc0 = MFMA(a0l, b_h, acc0);  acc1 = MFMA(a1l, b_h, acc1);
        }
        float* P = (float*)(smem + L1_P);
#pragma unroll
        for (int r = 0; r < 4; r++) {
          P[(mat * 32 + lk * 4 + r) * 36 + ct * 16 + lr]      = acc0[r];
          P[(mat * 32 + 16 + lk * 4 + r) * 36 + ct * 16 + lr] = acc1[r];
        }
        __syncthreads();

        u32* WHi = (u32*)SPTR(S1, s & 1, 0);
        u32* WLo = (u32*)SPTR(S1, s & 1, 1);
        if (tid < 128) {
          int b = tid & 31, p = tid >> 5;  // p in 0..3
          float hv[2], rv[2];
#pragma unroll
          for (int q = 0; q < 2; q++) {
            int d = p * 2 + q;
            float pi = P[(d) * 36 + b]      + P[(32 + d) * 36 + b]      + bias1[d];
            float pf = P[(8 + d) * 36 + b]  + P[(32 + 8 + d) * 36 + b]  + bias1[8 + d];
            float pg = P[(16 + d) * 36 + b] + P[(32 + 16 + d) * 36 + b] + bias1[16 + d];
            float po = P[(24 + d) * 36 + b] + P[(32 + 24 + d) * 36 + b] + bias1[24 + d];
            float c = sigf(pf) * cbuf[d * 32 + b] + sigf(pi) * tanhf(pg);
            cbuf[d * 32 + b] = c;
            float h = sigf(po) * tanhf(c);
            hv[q] = h;
            rv[q] = h - (float)((bf16)h);
          }
          int widx = (dg * 64 + half * 32 + b) * 4 + p;
          st_agent32(WHi + widx, pack2(hv[0], hv[1]));
          st_agent32(WLo + widx, pack2(rv[0], rv[1]));
        }
      }
      if (s <= TT) gbar(flags, (u32)(s + 1));
    }
  } else {
    // ================= FC WG: out[b,t] = fc_w . h2[t] + fc_b =================
    float* fw  = (float*)smem;            // [256]
    float* red = (float*)(smem + 1024);   // [4][64]
    for (int i = tid; i < 256; i += NTHR) fw[i] = fcw[i];
    __syncthreads();
    const float fb = fcb[0];
    for (int s = 0; s <= TT + 1; s++) {
      if (s >= 2) {
        int t = s - 2;
        const u64* hi = (const u64*)SPTR(S1, (s - 1) & 1, 0);
        const u64* lo = (const u64*)SPTR(S1, (s - 1) & 1, 1);
        int b = tid & 63, q = tid >> 6;          // q = k-quarter
        float acc = 0.0f;
        for (int kb = q * 8; kb < q * 8 + 8; kb++) {
#pragma unroll
          for (int j = 0; j < 2; j++) {
            u64 vh = ld_agent64(hi + (kb * 64 + b) * 2 + j);
            u64 vl = ld_agent64(lo + (kb * 64 + b) * 2 + j);
            bf16x4 h4 = __builtin_bit_cast(bf16x4, vh);
            bf16x4 l4 = __builtin_bit_cast(bf16x4, vl);
#pragma unroll
            for (int e = 0; e < 4; e++)
              acc += ((float)h4[e] + (float)l4[e]) * fw[kb * 8 + j * 4 + e];
          }
        }
        red[q * 64 + b] = acc;
        __syncthreads();
        if (tid < 64)
          out[tid * TT + t] = red[tid] + red[64 + tid] + red[128 + tid] + red[192 + tid] + fb;
        __syncthreads();
      }
      if (s <= TT) gbar(flags, (u32)(s + 1));
    }
  }
}

extern "C" void kernel_launch(void* const* d_in, const int* in_sizes, int n_in,
                              void* d_out, int out_size, void* d_ws, size_t ws_size,
                              hipStream_t stream) {
  (void)in_sizes; (void)n_in; (void)out_size; (void)ws_size;
  hipFuncSetAttribute((const void*)lstm_persist,
                      hipFuncAttributeMaxDynamicSharedMemorySize, SMEM_BYTES);
  // re-initialize barrier flags and zero h-state buffers every call (deterministic)
  hipMemsetAsync(d_ws, 0, WS_TOTAL, stream);
  lstm_persist<<<dim3(NWG), dim3(NTHR), SMEM_BYTES, stream>>>(
      (const float*)d_in[0],
      (const float*)d_in[1], (const float*)d_in[2],
      (const float*)d_in[3], (const float*)d_in[4],
      (const float*)d_in[5], (const float*)d_in[6],
      (const float*)d_in[7], (const float*)d_in[8],
      (const float*)d_in[9], (const float*)d_in[10],
      (float*)d_out, (char*)d_ws);
}

// Round 3
// 24145.728 us; speedup vs baseline: 1.7957x; 1.0174x over previous
//
#include <hip/hip_runtime.h>

// ---------------- problem constants ----------------
#define TT 2048
#define BB 64
#define HH 256

#define NW0 32          // layer-0 workgroups (8 h-dims each, all 64 batches)
#define NW1 64          // layer-1 workgroups (8 h-dims x 32-batch half)
#define NWG 97          // 32 + 64 + 1 FC
#define NTHR 256

// ---------------- workspace layout (bytes) ----------------
#define WS_FLAGS 0                   // u32[128]
#define WS_S0    1024                // [2 buf][2 comp][32 kblk][64 b][8] bf16 = 131072 B
#define WS_S1    (1024 + 131072)
#define WS_TOTAL (1024 + 2*131072)

// ---------------- LDS layouts (byte offsets into dynamic smem) ----------------
// Layer-0 role:
#define L0_AHI 0          // [32 kblk][32 row][8] bf16 (16 KB)
#define L0_ALO 16384
#define L0_BHI 32768      // [32 kblk][64 b][8] bf16 (32 KB)
#define L0_BLO 65536
#define L0_P   98304      // [32][68] f32 (8704 B)
#define L0_C   107008     // [512] f32
#define L0_WIB 109056     // [32] f32
#define L0_BIAS 109184    // [32] f32
#define L0_X   109312     // [64] f32
// Layer-1 role:
#define L1_AIH_HI 0       // each [32 kblk][32 row][8] bf16 (16 KB)
#define L1_AIH_LO 16384
#define L1_AHH_HI 32768
#define L1_AHH_LO 49152
#define L1_B1HI   65536   // each [32 kblk][32 b][8] bf16 (16 KB)
#define L1_B1LO   81920
#define L1_B2HI   98304
#define L1_B2LO   114688
#define L1_P      131072  // [64][36] f32 (9216 B)
#define L1_C      140288  // [256] f32
#define L1_BIAS   141312  // [32] f32
#define SMEM_BYTES 141440

typedef __bf16 bf16;
typedef __bf16 bf16x8 __attribute__((ext_vector_type(8)));
typedef __bf16 bf16x4 __attribute__((ext_vector_type(4)));
typedef float f32x4 __attribute__((ext_vector_type(4)));
typedef unsigned int u32;
typedef unsigned long long u64;
typedef unsigned short u16;

__device__ __forceinline__ f32x4 MFMA(bf16x8 a, bf16x8 b, f32x4 c) {
  return __builtin_amdgcn_mfma_f32_16x16x32_bf16(a, b, c, 0, 0, 0);
}
__device__ __forceinline__ float sigf(float v) { return 1.0f / (1.0f + __expf(-v)); }

// agent-scope (L2-bypassing) accessors — all cross-WG data goes through these.
// Data stores are sc1 write-through, so L2 never holds dirty cross-WG lines and
// NO buffer_wbl2 / buffer_inv / threadfence is required anywhere.
__device__ __forceinline__ u64 ld_agent64(const u64* p) {
  return __hip_atomic_load(p, __ATOMIC_RELAXED, __HIP_MEMORY_SCOPE_AGENT);
}
__device__ __forceinline__ void st_agent32(u32* p, u32 v) {
  __hip_atomic_store(p, v, __ATOMIC_RELAXED, __HIP_MEMORY_SCOPE_AGENT);
}

// single-round all-to-all device barrier, fence-free.
// __syncthreads drains every wave's vmcnt (sc1 stores ack'd at the coherence
// point => device-visible) BEFORE the flag store, so a RELAXED flag store is
// sufficient — no buffer_wbl2 (this was the 9 us/step cost of RELEASE).
__device__ __forceinline__ void gbar(u32* flags, u32 v) {
  __syncthreads();
  if (threadIdx.x == 0) {
    asm volatile("s_waitcnt vmcnt(0)" ::: "memory");  // belt-and-braces
    __hip_atomic_store(&flags[blockIdx.x], v, __ATOMIC_RELAXED, __HIP_MEMORY_SCOPE_AGENT);
  }
  if (threadIdx.x < 64) {
    const int l = threadIdx.x;
    const bool two = (l + 64) < NWG;
    for (;;) {
      u32 a = __hip_atomic_load(&flags[l], __ATOMIC_RELAXED, __HIP_MEMORY_SCOPE_AGENT);
      u32 b = two ? __hip_atomic_load(&flags[l + 64], __ATOMIC_RELAXED, __HIP_MEMORY_SCOPE_AGENT) : v;
      if (__all((int)(a >= v && b >= v))) break;
    }
  }
  __syncthreads();
}

__device__ __forceinline__ u32 pack2(float a, float b) {
  u16 pa = __builtin_bit_cast(u16, (bf16)a);
  u16 pb = __builtin_bit_cast(u16, (bf16)b);
  return ((u32)pb << 16) | pa;
}

// S-buffer pointer: [buf][comp] blocks of 32*64*8 = 16384 bf16 (32 KB)
#define SPTR(base, buf, comp) ((base) + (((buf)*2 + (comp)) << 14))

extern "C" __global__ __launch_bounds__(NTHR)
void lstm_persist(const float* __restrict__ x,
                  const float* __restrict__ Wih0, const float* __restrict__ Whh0,
                  const float* __restrict__ bih0, const float* __restrict__ bhh0,
                  const float* __restrict__ Wih1, const float* __restrict__ Whh1,
                  const float* __restrict__ bih1, const float* __restrict__ bhh1,
                  const float* __restrict__ fcw, const float* __restrict__ fcb,
                  float* __restrict__ out, char* __restrict__ ws)
{
  extern __shared__ char smem[];
  const int tid = threadIdx.x;
  const int wg = blockIdx.x;
  u32* flags = (u32*)(ws + WS_FLAGS);
  bf16* S0 = (bf16*)(ws + WS_S0);
  bf16* S1 = (bf16*)(ws + WS_S1);

  if (wg < NW0) {
    // ================= LAYER-0 WG: dims [wg*8, wg*8+8), batches 0..63 =================
    bf16x8* Ahi = (bf16x8*)(smem + L0_AHI);
    bf16x8* Alo = (bf16x8*)(smem + L0_ALO);
    float* wib  = (float*)(smem + L0_WIB);
    float* bias = (float*)(smem + L0_BIAS);
    float* cbuf = (float*)(smem + L0_C);
    float* xb   = (float*)(smem + L0_X);

    // one-time: Whh0 slice -> split-bf16 k-panel fragments (normal cached loads)
    for (int i = tid; i < 32 * 32; i += NTHR) {  // i = row*32 + kblk
      int row = i >> 5, kb = i & 31;
      int gate = row >> 3, d = row & 7;
      int grow = gate * 256 + wg * 8 + d;
      const float* src = Whh0 + grow * 256 + kb * 8;
      bf16x8 hi, lo;
#pragma unroll
      for (int e = 0; e < 8; e++) {
        float v = src[e];
        bf16 h = (bf16)v;
        hi[e] = h;
        lo[e] = (bf16)(v - (float)h);
      }
      Ahi[kb * 32 + row] = hi;
      Alo[kb * 32 + row] = lo;
    }
    if (tid < 32) {
      int gate = tid >> 3, d = tid & 7;
      int grow = gate * 256 + wg * 8 + d;
      wib[tid]  = Wih0[grow];
      bias[tid] = bih0[grow] + bhh0[grow];
    }
    for (int i = tid; i < 512; i += NTHR) cbuf[i] = 0.0f;

    for (int s = 0; s <= TT + 1; s++) {
      if (s < TT) {
        // stage h0[s-1] (hi+lo) into LDS via agent-scope u64 loads
        const u64* gh = (const u64*)SPTR(S0, (s - 1) & 1, 0);
        const u64* gl = (const u64*)SPTR(S0, (s - 1) & 1, 1);
        u64* bh = (u64*)(smem + L0_BHI);
        u64* bl = (u64*)(smem + L0_BLO);
        for (int i = tid; i < 4096; i += NTHR) {
          bh[i] = ld_agent64(gh + i);
          bl[i] = ld_agent64(gl + i);
        }
        if (tid < 64) xb[tid] = x[tid * TT + s];   // cached; stays in L2
        __syncthreads();

        const int w = tid >> 6, l = tid & 63, lr = l & 15, lk = l >> 4;
        const bf16x8* Ah = (const bf16x8*)(smem + L0_AHI);
        const bf16x8* Al = (const bf16x8*)(smem + L0_ALO);
        const bf16x8* Bh = (const bf16x8*)(smem + L0_BHI);
        const bf16x8* Bl = (const bf16x8*)(smem + L0_BLO);
        f32x4 acc0 = {0.f, 0.f, 0.f, 0.f}, acc1 = {0.f, 0.f, 0.f, 0.f};
#pragma unroll
        for (int ks = 0; ks < 8; ks++) {
          int kb = ks * 4 + lk;
          bf16x8 a0h = Ah[kb * 32 + lr],      a1h = Ah[kb * 32 + 16 + lr];
          bf16x8 a0l = Al[kb * 32 + lr],      a1l = Al[kb * 32 + 16 + lr];
          bf16x8 b_h = Bh[kb * 64 + w * 16 + lr];
          bf16x8 b_l = Bl[kb * 64 + w * 16 + lr];
          acc0 = MFMA(a0h, b_h, acc0);  acc1 = MFMA(a1h, b_h, acc1);
          acc0 = MFMA(a0h, b_l, acc0);  acc1 = MFMA(a1h, b_l, acc1);
          acc0 = MFMA(a0l, b_h, acc0);  acc1 = MFMA(a1l, b_h, acc1);
        }
        float* P = (float*)(smem + L0_P);
#pragma unroll
        for (int r = 0; r < 4; r++) {
          P[(lk * 4 + r) * 68 + w * 16 + lr]      = acc0[r];
          P[(16 + lk * 4 + r) * 68 + w * 16 + lr] = acc1[r];
        }
        __syncthreads();

        // gate update; each thread does 2 adjacent dims for one batch, packs u32
        u32* WHi = (u32*)SPTR(S0, s & 1, 0);
        u32* WLo = (u32*)SPTR(S0, s & 1, 1);
        {
          int b = tid >> 2, p = tid & 3;
          float xv = xb[b];
          float hv[2], rv[2];
#pragma unroll
          for (int q = 0; q < 2; q++) {
            int d = p * 2 + q;
            float pi = P[(d) * 68 + b]      + wib[d] * xv      + bias[d];
            float pf = P[(8 + d) * 68 + b]  + wib[8 + d] * xv  + bias[8 + d];
            float pg = P[(16 + d) * 68 + b] + wib[16 + d] * xv + bias[16 + d];
            float po = P[(24 + d) * 68 + b] + wib[24 + d] * xv + bias[24 + d];
            float c = sigf(pf) * cbuf[d * 64 + b] + sigf(pi) * tanhf(pg);
            cbuf[d * 64 + b] = c;
            float h = sigf(po) * tanhf(c);
            hv[q] = h;
            rv[q] = h - (float)((bf16)h);
          }
          int widx = (wg * 64 + b) * 4 + p;
          st_agent32(WHi + widx, pack2(hv[0], hv[1]));
          st_agent32(WLo + widx, pack2(rv[0], rv[1]));
        }
      }
      if (s <= TT) gbar(flags, (u32)(s + 1));
    }
  } else if (wg < NW0 + NW1) {
    // ================= LAYER-1 WG: dims [dg*8,+8), batches [half*32,+32) =================
    const int wg1 = wg - NW0;
    const int dg = wg1 & 31;
    const int half = wg1 >> 5;
    bf16x8* AihH = (bf16x8*)(smem + L1_AIH_HI);
    bf16x8* AihL = (bf16x8*)(smem + L1_AIH_LO);
    bf16x8* AhhH = (bf16x8*)(smem + L1_AHH_HI);
    bf16x8* AhhL = (bf16x8*)(smem + L1_AHH_LO);
    float* bias1 = (float*)(smem + L1_BIAS);
    float* cbuf  = (float*)(smem + L1_C);

    for (int i = tid; i < 32 * 32; i += NTHR) {
      int row = i >> 5, kb = i & 31;
      int gate = row >> 3, d = row & 7;
      int grow = gate * 256 + dg * 8 + d;
      {
        const float* src = Wih1 + grow * 256 + kb * 8;
        bf16x8 hi, lo;
#pragma unroll
        for (int e = 0; e < 8; e++) { float v = src[e]; bf16 h = (bf16)v; hi[e] = h; lo[e] = (bf16)(v - (float)h); }
        AihH[kb * 32 + row] = hi; AihL[kb * 32 + row] = lo;
      }
      {
        const float* src = Whh1 + grow * 256 + kb * 8;
        bf16x8 hi, lo;
#pragma unroll
        for (int e = 0; e < 8; e++) { float v = src[e]; bf16 h = (bf16)v; hi[e] = h; lo[e] = (bf16)(v - (float)h); }
        AhhH[kb * 32 + row] = hi; AhhL[kb * 32 + row] = lo;
      }
    }
    if (tid < 32) {
      int gate = tid >> 3, d = tid & 7;
      int grow = gate * 256 + dg * 8 + d;
      bias1[tid] = bih1[grow] + bhh1[grow];
    }
    for (int i = tid; i < 256; i += NTHR) cbuf[i] = 0.0f;

    for (int s = 0; s <= TT + 1; s++) {
      if (s >= 1 && s <= TT) {
        const int rb = (s - 1) & 1;
        const u64* g1h = (const u64*)SPTR(S0, rb, 0);
        const u64* g1l = (const u64*)SPTR(S0, rb, 1);
        const u64* g2h = (const u64*)SPTR(S1, rb, 0);
        const u64* g2l = (const u64*)SPTR(S1, rb, 1);
        u64* b1h = (u64*)(smem + L1_B1HI);
        u64* b1l = (u64*)(smem + L1_B1LO);
        u64* b2h = (u64*)(smem + L1_B2HI);
        u64* b2l = (u64*)(smem + L1_B2LO);
        for (int i = tid; i < 2048; i += NTHR) {
          // LDS u64 idx i = kb*64 + (b*2+j), b<32 ; global idx = kb*128 + half*64 + (b*2+j)
          int gi = i + ((i >> 6) << 6) + half * 64;
          b1h[i] = ld_agent64(g1h + gi);
          b1l[i] = ld_agent64(g1l + gi);
          b2h[i] = ld_agent64(g2h + gi);
          b2l[i] = ld_agent64(g2l + gi);
        }
        __syncthreads();

        const int w = tid >> 6, l = tid & 63, lr = l & 15, lk = l >> 4;
        const int mat = w >> 1, ct = w & 1;
        const bf16x8* Ah = (const bf16x8*)(smem + (mat ? L1_AHH_HI : L1_AIH_HI));
        const bf16x8* Al = (const bf16x8*)(smem + (mat ? L1_AHH_LO : L1_AIH_LO));
        const bf16x8* Bh = (const bf16x8*)(smem + (mat ? L1_B2HI : L1_B1HI));
        const bf16x8* Bl = (const bf16x8*)(smem + (mat ? L1_B2LO : L1_B1LO));
        f32x4 acc0 = {0.f, 0.f, 0.f, 0.f}, acc1 = {0.f, 0.f, 0.f, 0.f};
#pragma unroll
        for (int ks = 0; ks < 8; ks++) {
          int kb = ks * 4 + lk;
          bf16x8 a0h = Ah[kb * 32 + lr],      a1h = Ah[kb * 32 + 16 + lr];
          bf16x8 a0l = Al[kb * 32 + lr],      a1l = Al[kb * 32 + 16 + lr];
          bf16x8 b_h = Bh[kb * 32 + ct * 16 + lr];
          bf16x8 b_l = Bl[kb * 32 + ct * 16 + lr];
          acc0 = MFMA(a0h, b_h, acc0);  acc1 = MFMA(a1h, b_h, acc1);
          acc0 = MFMA(a0h, b_l, acc0);  acc1 = MFMA(a1h, b_l, acc1);
          acc0 = MFMA(a0l, b_h, acc0);  acc1 = MFMA(a1l, b_h, acc1);
        }
        float* P = (float*)(smem + L1_P);
#pragma unroll
        for (int r = 0; r < 4; r++) {
          P[(mat * 32 + lk * 4 + r) * 36 + ct * 16 + lr]      = acc0[r];
          P[(mat * 32 + 16 + lk * 4 + r) * 36 + ct * 16 + lr] = acc1[r];
        }
        __syncthreads();

        u32* WHi = (u32*)SPTR(S1, s & 1, 0);
        u32* WLo = (u32*)SPTR(S1, s & 1, 1);
        if (tid < 128) {
          int b = tid & 31, p = tid >> 5;  // p in 0..3
          float hv[2], rv[2];
#pragma unroll
          for (int q = 0; q < 2; q++) {
            int d = p * 2 + q;
            float pi = P[(d) * 36 + b]      + P[(32 + d) * 36 + b]      + bias1[d];
            float pf = P[(8 + d) * 36 + b]  + P[(32 + 8 + d) * 36 + b]  + bias1[8 + d];
            float pg = P[(16 + d) * 36 + b] + P[(32 + 16 + d) * 36 + b] + bias1[16 + d];
            float po = P[(24 + d) * 36 + b] + P[(32 + 24 + d) * 36 + b] + bias1[24 + d];
            float c = sigf(pf) * cbuf[d * 32 + b] + sigf(pi) * tanhf(pg);
            cbuf[d * 32 + b] = c;
            float h = sigf(po) * tanhf(c);
            hv[q] = h;
            rv[q] = h - (float)((bf16)h);
          }
          int widx = (dg * 64 + half * 32 + b) * 4 + p;
          st_agent32(WHi + widx, pack2(hv[0], hv[1]));
          st_agent32(WLo + widx, pack2(rv[0], rv[1]));
        }
      }
      if (s <= TT) gbar(flags, (u32)(s + 1));
    }
  } else {
    // ================= FC WG: out[b,t] = fc_w . h2[t] + fc_b =================
    float* fw  = (float*)smem;            // [256]
    float* red = (float*)(smem + 1024);   // [4][64]
    for (int i = tid; i < 256; i += NTHR) fw[i] = fcw[i];
    __syncthreads();
    const float fb = fcb[0];
    for (int s = 0; s <= TT + 1; s++) {
      if (s >= 2) {
        int t = s - 2;
        const u64* hi = (const u64*)SPTR(S1, (s - 1) & 1, 0);
        const u64* lo = (const u64*)SPTR(S1, (s - 1) & 1, 1);
        int b = tid & 63, q = tid >> 6;          // q = k-quarter
        float acc = 0.0f;
        for (int kb = q * 8; kb < q * 8 + 8; kb++) {
#pragma unroll
          for (int j = 0; j < 2; j++) {
            u64 vh = ld_agent64(hi + (kb * 64 + b) * 2 + j);
            u64 vl = ld_agent64(lo + (kb * 64 + b) * 2 + j);
            bf16x4 h4 = __builtin_bit_cast(bf16x4, vh);
            bf16x4 l4 = __builtin_bit_cast(bf16x4, vl);
#pragma unroll
            for (int e = 0; e < 4; e++)
              acc += ((float)h4[e] + (float)l4[e]) * fw[kb * 8 + j * 4 + e];
          }
        }
        red[q * 64 + b] = acc;
        __syncthreads();
        if (tid < 64)
          out[tid * TT + t] = red[tid] + red[64 + tid] + red[128 + tid] + red[192 + tid] + fb;
        __syncthreads();
      }
      if (s <= TT) gbar(flags, (u32)(s + 1));
    }
  }
}

extern "C" void kernel_launch(void* const* d_in, const int* in_sizes, int n_in,
                              void* d_out, int out_size, void* d_ws, size_t ws_size,
                              hipStream_t stream) {
  (void)in_sizes; (void)n_in; (void)out_size; (void)ws_size;
  hipFuncSetAttribute((const void*)lstm_persist,
                      hipFuncAttributeMaxDynamicSharedMemorySize, SMEM_BYTES);
  // re-initialize barrier flags and zero h-state buffers every call (deterministic)
  hipMemsetAsync(d_ws, 0, WS_TOTAL, stream);
  lstm_persist<<<dim3(NWG), dim3(NTHR), SMEM_BYTES, stream>>>(
      (const float*)d_in[0],
      (const float*)d_in[1], (const float*)d_in[2],
      (const float*)d_in[3], (const float*)d_in[4],
      (const float*)d_in[5], (const float*)d_in[6],
      (const float*)d_in[7], (const float*)d_in[8],
      (const float*)d_in[9], (const float*)d_in[10],
      (float*)d_out, (char*)d_ws);
}

// Round 5
// 10906.564 us; speedup vs baseline: 3.9754x; 2.2139x over previous
//
#include <hip/hip_runtime.h>

// ================= problem constants =================
#define TT 2048
#define NTHR 512
#define NWG 128          // round-robin blockIdx%8 -> XCD (locality heuristic only)

// ================= workspace layout (bytes) =================
#define ABORT_O  0
#define E0_O     128      // L0 progress epoch (deep)
#define E1P_O    256      // L1 progress epoch (deep, backpressure)
#define GFL0A_O  512      // L0 flags, local rail: 16 x 128B
#define GFL0B_O  2560     // L0 flags, deep rail
#define GFL1A_O  4608
#define GFL1B_O  6656
#define H0EXP_O  16384    // 4 ring slots x 64KB: [comp2][kb32][b64][8] bf16
#define H1R_O    278528   // 2 parity bufs x 64KB
#define WS_TOTAL 409600

// ================= LDS layout (byte offsets into dynamic smem) =================
#define A0_HI   0         // L0: Whh0 slice [kb32][row64][8] bf16
#define A0_LO   32768
#define A_IH_HI 0         // L1: four 32KB weight blocks
#define A_IH_LO 32768
#define A_HH_HI 65536
#define A_HH_LO 98304
#define P_O     131072    // [64][68] f32 (17408 B)
#define CB_O    148480    // [16][64] f32 c-state
#define BIAS_O  152576    // [64] f32
#define FWL_O   152832    // [16] f32 (L1 only)
#define WIB_O   152896    // [64] f32 (L0 only)
#define XB_O    153152    // [64] f32 (L0 only)
#define SMEM_BYTES 153408

typedef __bf16 bf16;
typedef __bf16 bf16x8 __attribute__((ext_vector_type(8)));
typedef float f32x4 __attribute__((ext_vector_type(4)));
typedef unsigned int u32;
typedef u32 u32x4 __attribute__((ext_vector_type(4)));
typedef unsigned short u16;

__device__ __forceinline__ f32x4 MFMA(bf16x8 a, bf16x8 b, f32x4 c) {
  return __builtin_amdgcn_mfma_f32_16x16x32_bf16(a, b, c, 0, 0, 0);
}
__device__ __forceinline__ float sigf(float v) { return 1.0f / (1.0f + __expf(-v)); }
__device__ __forceinline__ u16 bfbits(float f) { return __builtin_bit_cast(u16, (bf16)f); }
__device__ __forceinline__ u32 pack2(float a, float b) {
  return ((u32)bfbits(b) << 16) | bfbits(a);
}

// ---------- transport primitives ----------
// deep (sc0 sc1): write-through / read at Infinity Cache — device-coherent (R3-proven).
// local (plain store / sc0 load): same-XCD L2 fast path — OPTIMIZATION ONLY, never
// required for correctness (dual-rail max with the deep value).
__device__ __forceinline__ bf16x8 ld16d(const void* p) {
  u32x4 v;
  asm volatile("global_load_dwordx4 %0, %1, off sc0 sc1" : "=v"(v) : "v"(p));
  return __builtin_bit_cast(bf16x8, v);
}
__device__ __forceinline__ void wait_all_loads() {
  asm volatile("s_waitcnt vmcnt(0)" ::: "memory");
  __builtin_amdgcn_sched_barrier(0);
}
__device__ __forceinline__ void drain_stores() {
  asm volatile("s_waitcnt vmcnt(0)" ::: "memory");
}
__device__ __forceinline__ void st32d(u32* p, u32 v) {
  asm volatile("global_store_dword %0, %1, off sc0 sc1" :: "v"(p), "v"(v) : "memory");
}
__device__ __forceinline__ void post_flag(u32* pA, u32* pB, u32 v) {
  asm volatile("global_store_dword %0, %1, off"         :: "v"(pA), "v"(v) : "memory");
  asm volatile("global_store_dword %0, %1, off sc0 sc1" :: "v"(pB), "v"(v) : "memory");
}
// bounded dual-rail wait: poll max(local, deep) >= need across the wave;
// cap -> set global abort -> everyone bails fast (FAIL loudly, never hang).
__device__ __forceinline__ void wait_ge(const u32* pA, const u32* pB, u32 need, u32* abortp) {
  int it = 0;
  for (;;) {
    u32 va, vb;
    asm volatile("global_load_dword %0, %1, off sc0\n\ts_waitcnt vmcnt(0)"
                 : "=v"(va) : "v"(pA) : "memory");
    asm volatile("global_load_dword %0, %1, off sc0 sc1\n\ts_waitcnt vmcnt(0)"
                 : "=v"(vb) : "v"(pB) : "memory");
    u32 v = va > vb ? va : vb;
    if (__all((int)(v >= need))) break;
    if (((++it) & 63) == 0) {
      u32 ab;
      asm volatile("global_load_dword %0, %1, off sc0 sc1\n\ts_waitcnt vmcnt(0)"
                   : "=v"(ab) : "v"(abortp) : "memory");
      if (__any((int)(ab != 0))) break;
      if (it >= (1 << 18)) {
        if (threadIdx.x == 0) st32d(abortp, 1u);
        break;
      }
    }
  }
}

extern "C" __global__ __launch_bounds__(NTHR, 2)
void lstm_persist(const float* __restrict__ x,
                  const float* __restrict__ Wih0, const float* __restrict__ Whh0,
                  const float* __restrict__ bih0, const float* __restrict__ bhh0,
                  const float* __restrict__ Wih1, const float* __restrict__ Whh1,
                  const float* __restrict__ bih1, const float* __restrict__ bhh1,
                  const float* __restrict__ fcw, const float* __restrict__ fcb,
                  float* __restrict__ out, char* __restrict__ ws)
{
  extern __shared__ char smem[];
  const int tid  = threadIdx.x;
  const int wg   = blockIdx.x;
  const int role = wg & 7;
  const int slot = wg >> 3;     // 0..15 within a group
  if (role > 1) return;         // only roles 0 (L0) and 1 (L1) work

  u32* abortp = (u32*)(ws + ABORT_O);
  u32* e0     = (u32*)(ws + E0_O);
  u32* e1p    = (u32*)(ws + E1P_O);

  const int w = tid >> 6, l = tid & 63, lr = l & 15, lk = l >> 4;
  const int rowb = (w & 1) * 32, colb = (w >> 1) * 16;

  float* P    = (float*)(smem + P_O);
  float* cbuf = (float*)(smem + CB_O);
  float* bias = (float*)(smem + BIAS_O);

  if (role == 0) {
    // ================= LAYER-0: WG owns h-dims [slot*16,+16), all 64 batches =================
    bf16x8* Ahi = (bf16x8*)(smem + A0_HI);
    bf16x8* Alo = (bf16x8*)(smem + A0_LO);
    float* wib  = (float*)(smem + WIB_O);
    float* xb   = (float*)(smem + XB_O);

    for (int i = tid; i < 2048; i += NTHR) {   // i = row*32 + kb
      int row = i >> 5, kb = i & 31;
      int grow = (row >> 4) * 256 + slot * 16 + (row & 15);
      const float* src = Whh0 + grow * 256 + kb * 8;
      bf16x8 hi, lo;
#pragma unroll
      for (int e = 0; e < 8; e++) { float v = src[e]; bf16 h = (bf16)v; hi[e] = h; lo[e] = (bf16)(v - (float)h); }
      Ahi[kb * 64 + row] = hi;  Alo[kb * 64 + row] = lo;
    }
    if (tid < 64) {
      int grow = (tid >> 4) * 256 + slot * 16 + (tid & 15);
      wib[tid]  = Wih0[grow];
      bias[tid] = bih0[grow] + bhh0[grow];
    }
    for (int i = tid; i < 1024; i += NTHR) cbuf[i] = 0.0f;
    __syncthreads();

    u32* gfA = (u32*)(ws + GFL0A_O);
    u32* gfB = (u32*)(ws + GFL0B_O);

    for (int s = 0; s <= TT; s++) {
      if (tid < 64) {
        const u32 *pA, *pB; u32 need;
        if (tid < 16)       { pA = gfA + tid * 32; pB = gfB + tid * 32; need = (u32)s; }
        else if (tid == 16) { pA = e1p; pB = e1p; need = (s >= 4 && s < TT) ? (u32)(s - 3) : 0u; }
        else                { pA = gfA; pB = gfB; need = 0u; }
        wait_ge(pA, pB, need, abortp);
        if (tid == 0 && slot == 0 && s > 0) st32d(e0, (u32)s);   // h0[s-1] globally visible
      }
      if (s == TT) break;
      __syncthreads();

      // B operands: h0[s-1] from export ring (deep), direct to VGPR
      const char* hp = ws + H0EXP_O + (size_t)((s - 1) & 3) * 65536;
      bf16x8 bh[8], bl[8];
#pragma unroll
      for (int ks = 0; ks < 8; ks++) {
        int kb = ks * 4 + lk;
        const char* p = hp + (size_t)(kb * 64 + colb + lr) * 16;
        bh[ks] = ld16d(p);
        bl[ks] = ld16d(p + 32768);
      }
      if (tid < 64) xb[tid] = x[tid * TT + s];
      wait_all_loads();

      f32x4 acc0 = {0.f,0.f,0.f,0.f}, acc1 = {0.f,0.f,0.f,0.f};
#pragma unroll
      for (int ks = 0; ks < 8; ks++) {
        int kb = ks * 4 + lk;
        bf16x8 a0h = Ahi[kb * 64 + rowb + lr], a1h = Ahi[kb * 64 + rowb + 16 + lr];
        bf16x8 a0l = Alo[kb * 64 + rowb + lr], a1l = Alo[kb * 64 + rowb + 16 + lr];
        acc0 = MFMA(a0h, bh[ks], acc0);  acc1 = MFMA(a1h, bh[ks], acc1);
        acc0 = MFMA(a0h, bl[ks], acc0);  acc1 = MFMA(a1h, bl[ks], acc1);
        acc0 = MFMA(a0l, bh[ks], acc0);  acc1 = MFMA(a1l, bh[ks], acc1);
      }
#pragma unroll
      for (int r = 0; r < 4; r++) {
        P[(rowb + lk * 4 + r) * 68 + colb + lr]      = acc0[r];
        P[(rowb + 16 + lk * 4 + r) * 68 + colb + lr] = acc1[r];
      }
      __syncthreads();

      // gates: thread -> (b = tid>>3, two dims d = 2p, 2p+1)
      {
        u32* eh = (u32*)(ws + H0EXP_O + (size_t)(s & 3) * 65536);
        u32* el = (u32*)((char*)eh + 32768 / 4 * 0 + 32768);
        int b = tid >> 3, p = tid & 7;
        float xv = xb[b];
        float hv[2], rv[2];
#pragma unroll
        for (int q = 0; q < 2; q++) {
          int d = p * 2 + q;
          float pi = P[(d) * 68 + b]      + wib[d] * xv      + bias[d];
          float pf = P[(16 + d) * 68 + b] + wib[16 + d] * xv + bias[16 + d];
          float pg = P[(32 + d) * 68 + b] + wib[32 + d] * xv + bias[32 + d];
          float po = P[(48 + d) * 68 + b] + wib[48 + d] * xv + bias[48 + d];
          float c = sigf(pf) * cbuf[d * 64 + b] + sigf(pi) * tanhf(pg);
          cbuf[d * 64 + b] = c;
          float h = sigf(po) * tanhf(c);
          hv[q] = h;  rv[q] = h - (float)((bf16)h);
        }
        int kbg = slot * 2 + (p >> 2);
        u32 wi = (u32)((kbg * 64 + b) * 4 + (p & 3));
        st32d(eh + wi, pack2(hv[0], hv[1]));
        st32d(el + wi, pack2(rv[0], rv[1]));
      }
      drain_stores();          // every thread: its deep stores are device-visible
      __syncthreads();
      if (tid == 0) post_flag(gfA + slot * 32, gfB + slot * 32, (u32)(s + 1));
    }
  } else {
    // ================= LAYER-1: WG owns h-dims [slot*16,+16), all 64 batches; FC inlined =================
    bf16x8* AihH = (bf16x8*)(smem + A_IH_HI);
    bf16x8* AihL = (bf16x8*)(smem + A_IH_LO);
    bf16x8* AhhH = (bf16x8*)(smem + A_HH_HI);
    bf16x8* AhhL = (bf16x8*)(smem + A_HH_LO);
    float* fwl   = (float*)(smem + FWL_O);

    for (int i = tid; i < 2048; i += NTHR) {
      int row = i >> 5, kb = i & 31;
      int grow = (row >> 4) * 256 + slot * 16 + (row & 15);
      {
        const float* src = Wih1 + grow * 256 + kb * 8;
        bf16x8 hi, lo;
#pragma unroll
        for (int e = 0; e < 8; e++) { float v = src[e]; bf16 h = (bf16)v; hi[e] = h; lo[e] = (bf16)(v - (float)h); }
        AihH[kb * 64 + row] = hi;  AihL[kb * 64 + row] = lo;
      }
      {
        const float* src = Whh1 + grow * 256 + kb * 8;
        bf16x8 hi, lo;
#pragma unroll
        for (int e = 0; e < 8; e++) { float v = src[e]; bf16 h = (bf16)v; hi[e] = h; lo[e] = (bf16)(v - (float)h); }
        AhhH[kb * 64 + row] = hi;  AhhL[kb * 64 + row] = lo;
      }
    }
    if (tid < 64) {
      int grow = (tid >> 4) * 256 + slot * 16 + (tid & 15);
      bias[tid] = bih1[grow] + bhh1[grow];
    }
    if (tid < 16) fwl[tid] = fcw[slot * 16 + tid];
    for (int i = tid; i < 1024; i += NTHR) cbuf[i] = 0.0f;
    __syncthreads();

    u32* gfA = (u32*)(ws + GFL1A_O);
    u32* gfB = (u32*)(ws + GFL1B_O);
    const float fb = fcb[0];

    for (int u = 0; u < TT; u++) {
      if (tid < 64) {
        const u32 *pA, *pB; u32 need;
        if (tid < 16)       { pA = gfA + tid * 32; pB = gfB + tid * 32; need = (u32)u; }
        else if (tid == 16) { pA = e0; pB = e0; need = (u32)(u + 1); }
        else                { pA = gfA; pB = gfB; need = 0u; }
        wait_ge(pA, pB, need, abortp);
        if (tid == 0 && slot == 0 && u > 0) st32d(e1p, (u32)u);  // finished u-1 (ring slot free)
      }
      __syncthreads();

      // B operands: h0[u] (export ring) + h1[u-1] (parity buffer), both deep
      const char* h0p = ws + H0EXP_O + (size_t)(u & 3) * 65536;
      const char* h1p = ws + H1R_O + (size_t)((u - 1) & 1) * 65536;
      bf16x8 b0h[8], b0l[8], b1h[8], b1l[8];
#pragma unroll
      for (int ks = 0; ks < 8; ks++) {
        int kb = ks * 4 + lk;
        const char* p0 = h0p + (size_t)(kb * 64 + colb + lr) * 16;
        const char* p1 = h1p + (size_t)(kb * 64 + colb + lr) * 16;
        b0h[ks] = ld16d(p0);  b0l[ks] = ld16d(p0 + 32768);
        b1h[ks] = ld16d(p1);  b1l[ks] = ld16d(p1 + 32768);
      }
      wait_all_loads();

      f32x4 acc0 = {0.f,0.f,0.f,0.f}, acc1 = {0.f,0.f,0.f,0.f};
#pragma unroll
      for (int ks = 0; ks < 8; ks++) {
        int kb = ks * 4 + lk;
        bf16x8 aih0 = AihH[kb * 64 + rowb + lr], aih1 = AihH[kb * 64 + rowb + 16 + lr];
        bf16x8 ail0 = AihL[kb * 64 + rowb + lr], ail1 = AihL[kb * 64 + rowb + 16 + lr];
        acc0 = MFMA(aih0, b0h[ks], acc0);  acc1 = MFMA(aih1, b0h[ks], acc1);
        acc0 = MFMA(aih0, b0l[ks], acc0);  acc1 = MFMA(aih1, b0l[ks], acc1);
        acc0 = MFMA(ail0, b0h[ks], acc0);  acc1 = MFMA(ail1, b0h[ks], acc1);
        bf16x8 ahh0 = AhhH[kb * 64 + rowb + lr], ahh1 = AhhH[kb * 64 + rowb + 16 + lr];
        bf16x8 ahl0 = AhhL[kb * 64 + rowb + lr], ahl1 = AhhL[kb * 64 + rowb + 16 + lr];
        acc0 = MFMA(ahh0, b1h[ks], acc0);  acc1 = MFMA(ahh1, b1h[ks], acc1);
        acc0 = MFMA(ahh0, b1l[ks], acc0);  acc1 = MFMA(ahh1, b1l[ks], acc1);
        acc0 = MFMA(ahl0, b1h[ks], acc0);  acc1 = MFMA(ahl1, b1h[ks], acc1);
      }
#pragma unroll
      for (int r = 0; r < 4; r++) {
        P[(rowb + lk * 4 + r) * 68 + colb + lr]      = acc0[r];
        P[(rowb + 16 + lk * 4 + r) * 68 + colb + lr] = acc1[r];
      }
      __syncthreads();

      // gates + h1 write (ring, deep) + stash h (f32) into P rows 0-15 for FC
      {
        u32* rh = (u32*)(ws + H1R_O + (size_t)(u & 1) * 65536);
        u32* rl = (u32*)((char*)rh + 32768);
        int b = tid >> 3, p = tid & 7;
        float hv[2], rv[2];
#pragma unroll
        for (int q = 0; q < 2; q++) {
          int d = p * 2 + q;
          float pi = P[(d) * 68 + b]      + bias[d];
          float pf = P[(16 + d) * 68 + b] + bias[16 + d];
          float pg = P[(32 + d) * 68 + b] + bias[32 + d];
          float po = P[(48 + d) * 68 + b] + bias[48 + d];
          float c = sigf(pf) * cbuf[d * 64 + b] + sigf(pi) * tanhf(pg);
          cbuf[d * 64 + b] = c;
          float h = sigf(po) * tanhf(c);
          hv[q] = h;  rv[q] = h - (float)((bf16)h);
          P[d * 68 + b] = h;      // own cell: read-then-write by same thread only
        }
        int kbg = slot * 2 + (p >> 2);
        u32 wi = (u32)((kbg * 64 + b) * 4 + (p & 3));
        st32d(rh + wi, pack2(hv[0], hv[1]));
        st32d(rl + wi, pack2(rv[0], rv[1]));
      }
      drain_stores();
      __syncthreads();

      // FC partial: out[b,u] += sum_d fwl[d]*h[d][b]  (+ fc_b once, via slot 0)
      if (tid < 64) {
        float acc = 0.0f;
#pragma unroll
        for (int d = 0; d < 16; d++) acc += fwl[d] * P[d * 68 + tid];
        if (slot == 0) acc += fb;
        atomicAdd(out + (size_t)tid * TT + u, acc);
      }
      if (tid == 0) post_flag(gfA + slot * 32, gfB + slot * 32, (u32)(u + 1));
    }
  }
}

extern "C" void kernel_launch(void* const* d_in, const int* in_sizes, int n_in,
                              void* d_out, int out_size, void* d_ws, size_t ws_size,
                              hipStream_t stream) {
  (void)in_sizes; (void)n_in; (void)ws_size;
  hipFuncSetAttribute((const void*)lstm_persist,
                      hipFuncAttributeMaxDynamicSharedMemorySize, SMEM_BYTES);
  hipMemsetAsync(d_ws, 0, WS_TOTAL, stream);                    // flags/epochs/rings
  hipMemsetAsync(d_out, 0, (size_t)out_size * sizeof(float), stream);  // FC accumulates
  lstm_persist<<<dim3(NWG), dim3(NTHR), SMEM_BYTES, stream>>>(
      (const float*)d_in[0],
      (const float*)d_in[1], (const float*)d_in[2],
      (const float*)d_in[3], (const float*)d_in[4],
      (const float*)d_in[5], (const float*)d_in[6],
      (const float*)d_in[7], (const float*)d_in[8],
      (const float*)d_in[9], (const float*)d_in[10],
      (float*)d_out, (char*)d_ws);
}